// Round 1
// baseline (15407.475 us; speedup 1.0000x reference)
//
#include <hip/hip_runtime.h>
#include <math.h>

#define BATCH 2048
#define STEPS 512
#define EMB   128
#define HID   256
#define G3    768          // 3*HID
#define INGRU 641          // EMB + STEPS + 1

// ws layout (floats): WhT [256][768] | WxT [128][768] | Wcol [513][768]
#define WHT_OFF  0
#define WXT_OFF  (HID*G3)                 // 196608
#define WCOL_OFF (WXT_OFF + EMB*G3)       // 294912
#define WS_FLOATS (WCOL_OFF + 513*G3)     // 688896 floats = 2.63 MB

__global__ void prep_weights(const float* __restrict__ W_ih,
                             const float* __restrict__ W_hh,
                             float* __restrict__ ws) {
    int idx = blockIdx.x * blockDim.x + threadIdx.x;
    if (idx < HID * G3) {                  // WhT[k][g] = W_hh[g][k]
        int k = idx / G3, g = idx % G3;
        ws[WHT_OFF + idx] = W_hh[g * HID + k];
    }
    if (idx < EMB * G3) {                  // WxT[k][g] = W_ih[g][k]
        int k = idx / G3, g = idx % G3;
        ws[WXT_OFF + idx] = W_ih[g * INGRU + k];
    }
    if (idx < 513 * G3) {                  // Wcol[c][g] = W_ih[g][128+c]
        int c = idx / G3, g = idx % G3;
        ws[WCOL_OFF + idx] = W_ih[g * INGRU + EMB + c];
    }
}

// One workgroup = 8 batch rows, persistent over all 512 steps.
// 512 threads: rg = t>>8 picks rows rg*4..rg*4+3, gd = t&255 picks gate dim.
// Thread owns gates (gd, gd+256, gd+512) = (r,z,n) for its dim.
__global__ __launch_bounds__(512, 2) void gru_policy(
    const float* __restrict__ X,      // [B][STEPS][EMB]
    const float* __restrict__ ws,
    const float* __restrict__ b_ih,   // [768]
    const float* __restrict__ b_hh,   // [768]
    const float* __restrict__ W_cf,   // [2][256]
    const float* __restrict__ b_cf,   // [2]
    float* __restrict__ out)          // [B*STEPS] actions | [B*STEPS] pis
{
    const float* __restrict__ WhT  = ws + WHT_OFF;
    const float* __restrict__ WxT  = ws + WXT_OFF;
    const float* __restrict__ Wcol = ws + WCOL_OFF;

    __shared__ __align__(16) float h_lds[2][HID][12];  // [k][row], pad 12
    __shared__ __align__(16) float x_lds[EMB][12];
    __shared__ float red[8][8];                        // [wave][row(j)*2 + class]
    __shared__ int   tag_lds[8];

    const int t    = threadIdx.x;
    const int rg   = t >> 8;        // 0/1 -> rows 0-3 / 4-7
    const int gd   = t & 255;       // gate dim
    const int wv   = t >> 6;        // wave 0..7
    const int lane = t & 63;
    const size_t r0 = (size_t)blockIdx.x * 8;

    // hoisted per-thread constants
    const float bi0 = b_ih[gd], bi1 = b_ih[gd + HID], bi2 = b_ih[gd + 2*HID];
    const float bh0 = b_hh[gd], bh1 = b_hh[gd + HID], bh2 = b_hh[gd + 2*HID];
    const float wcf0 = W_cf[gd], wcf1 = W_cf[HID + gd];
    const float bc0 = b_cf[0], bc1 = b_cf[1];

    // init h=0, tags=0, load x for step 0
    for (int i = t; i < HID; i += 512) {
        #pragma unroll
        for (int r = 0; r < 8; ++r) h_lds[0][i][r] = 0.0f;
    }
    for (int i = t; i < 8 * EMB; i += 512) {
        int r = i >> 7, k = i & 127;
        x_lds[k][r] = X[(r0 + r) * (size_t)(STEPS * EMB) + k];
    }
    if (t < 8) tag_lds[t] = 0;
    __syncthreads();

    int cur = 0;
    for (int s = 0; s < STEPS; ++s) {
        float aI0[4], aI1[4], aI2[4], aH0[4], aH1[4], aH2[4];
        // init: biases + one-hot column gather (W_ih[:, 128+tag])
        #pragma unroll
        for (int j = 0; j < 4; ++j) {
            const int tg = tag_lds[rg * 4 + j];
            const float* wc = Wcol + (size_t)tg * G3 + gd;
            aI0[j] = bi0 + wc[0];
            aI1[j] = bi1 + wc[HID];
            aI2[j] = bi2 + wc[2 * HID];
            aH0[j] = bh0; aH1[j] = bh1; aH2[j] = bh2;
        }

        // ---- gh += h @ W_hh^T  (K = 256) ----
        {
            const float* hb = &h_lds[cur][0][rg * 4];
            const float* wp = WhT + gd;
            #pragma unroll 8
            for (int k = 0; k < HID; ++k) {
                const float4 hv = *(const float4*)(hb + k * 12);  // LDS broadcast
                const float w0 = wp[0], w1 = wp[HID], w2 = wp[2 * HID];
                wp += G3;
                aH0[0] = fmaf(w0, hv.x, aH0[0]);
                aH0[1] = fmaf(w0, hv.y, aH0[1]);
                aH0[2] = fmaf(w0, hv.z, aH0[2]);
                aH0[3] = fmaf(w0, hv.w, aH0[3]);
                aH1[0] = fmaf(w1, hv.x, aH1[0]);
                aH1[1] = fmaf(w1, hv.y, aH1[1]);
                aH1[2] = fmaf(w1, hv.z, aH1[2]);
                aH1[3] = fmaf(w1, hv.w, aH1[3]);
                aH2[0] = fmaf(w2, hv.x, aH2[0]);
                aH2[1] = fmaf(w2, hv.y, aH2[1]);
                aH2[2] = fmaf(w2, hv.z, aH2[2]);
                aH2[3] = fmaf(w2, hv.w, aH2[3]);
            }
        }
        // ---- gi += x @ W_ihx^T  (K = 128) ----
        {
            const float* xb = &x_lds[0][rg * 4];
            const float* wq = WxT + gd;
            #pragma unroll 8
            for (int k = 0; k < EMB; ++k) {
                const float4 xv = *(const float4*)(xb + k * 12);
                const float w0 = wq[0], w1 = wq[HID], w2 = wq[2 * HID];
                wq += G3;
                aI0[0] = fmaf(w0, xv.x, aI0[0]);
                aI0[1] = fmaf(w0, xv.y, aI0[1]);
                aI0[2] = fmaf(w0, xv.z, aI0[2]);
                aI0[3] = fmaf(w0, xv.w, aI0[3]);
                aI1[0] = fmaf(w1, xv.x, aI1[0]);
                aI1[1] = fmaf(w1, xv.y, aI1[1]);
                aI1[2] = fmaf(w1, xv.z, aI1[2]);
                aI1[3] = fmaf(w1, xv.w, aI1[3]);
                aI2[0] = fmaf(w2, xv.x, aI2[0]);
                aI2[1] = fmaf(w2, xv.y, aI2[1]);
                aI2[2] = fmaf(w2, xv.z, aI2[2]);
                aI2[3] = fmaf(w2, xv.w, aI2[3]);
            }
        }

        // ---- gates, h_new, classifier partials ----
        float p0[4], p1[4], hn[4];
        const float4 hp = *(const float4*)(&h_lds[cur][gd][rg * 4]);
        const float hpj[4] = {hp.x, hp.y, hp.z, hp.w};
        #pragma unroll
        for (int j = 0; j < 4; ++j) {
            const float rr = 1.0f / (1.0f + expf(-(aI0[j] + aH0[j])));
            const float zz = 1.0f / (1.0f + expf(-(aI1[j] + aH1[j])));
            const float nn = tanhf(aI2[j] + rr * aH2[j]);
            const float h  = (1.0f - zz) * nn + zz * hpj[j];
            hn[j] = h;
            p0[j] = h * wcf0;
            p1[j] = h * wcf1;
        }
        *(float4*)(&h_lds[cur ^ 1][gd][rg * 4]) =
            make_float4(hn[0], hn[1], hn[2], hn[3]);

        // wave-level reduce of classifier partials over the 256 gate dims
        #pragma unroll
        for (int m = 32; m >= 1; m >>= 1) {
            #pragma unroll
            for (int j = 0; j < 4; ++j) {
                p0[j] += __shfl_xor(p0[j], m, 64);
                p1[j] += __shfl_xor(p1[j], m, 64);
            }
        }
        if (lane == 0) {
            #pragma unroll
            for (int j = 0; j < 4; ++j) {
                red[wv][2 * j]     = p0[j];
                red[wv][2 * j + 1] = p1[j];
            }
        }
        __syncthreads();   // h_new, red visible; all GEMM LDS reads done

        // ---- softmax / argmax / tag update, one thread per row ----
        if (t < 8) {
            const int grp = (t >> 2) * 4;   // waves 0-3 hold rows 0-3, 4-7 rows 4-7
            const int j   = t & 3;
            float l0 = bc0, l1 = bc1;
            #pragma unroll
            for (int w = 0; w < 4; ++w) {
                l0 += red[grp + w][2 * j];
                l1 += red[grp + w][2 * j + 1];
            }
            const int act = (l1 > l0) ? 1 : 0;   // argmax ties -> index 0
            const float mx = fmaxf(l0, l1);
            const float e0 = expf(l0 - mx), e1 = expf(l1 - mx);
            const float pi = (act ? e1 : e0) / (e0 + e1);
            const size_t row = r0 + t;
            out[row * STEPS + s] = (float)act;
            out[(size_t)BATCH * STEPS + row * STEPS + s] = pi;
            tag_lds[t] += act;
        }

        // prefetch x for next step (x_lds free after first barrier)
        if (s + 1 < STEPS) {
            for (int i = t; i < 8 * EMB; i += 512) {
                const int r = i >> 7, k = i & 127;
                x_lds[k][r] =
                    X[(r0 + r) * (size_t)(STEPS * EMB) + (size_t)(s + 1) * EMB + k];
            }
        }
        __syncthreads();   // tags + x + h_new[nxt] ready for next step
        cur ^= 1;
    }
}

extern "C" void kernel_launch(void* const* d_in, const int* in_sizes, int n_in,
                              void* d_out, int out_size, void* d_ws, size_t ws_size,
                              hipStream_t stream) {
    const float* X    = (const float*)d_in[0];
    const float* W_ih = (const float*)d_in[1];
    const float* W_hh = (const float*)d_in[2];
    const float* b_ih = (const float*)d_in[3];
    const float* b_hh = (const float*)d_in[4];
    const float* W_cf = (const float*)d_in[5];
    const float* b_cf = (const float*)d_in[6];
    float* out = (float*)d_out;
    float* ws  = (float*)d_ws;

    prep_weights<<<(513 * G3 + 255) / 256, 256, 0, stream>>>(W_ih, W_hh, ws);
    gru_policy<<<BATCH / 8, 512, 0, stream>>>(X, ws, b_ih, b_hh, W_cf, b_cf, out);
}